// Round 1
// baseline (272.726 us; speedup 1.0000x reference)
//
#include <hip/hip_runtime.h>

// FieldAwareFMLayer: x (bs, 40, 39, 16) fp32.
// out[n] = sum_{0<=i<=j<=38} dot(x[n,i,j,:], x[n,j+1,i,:])
//
// Every element participates in exactly one product -> pure streaming,
// 204.5 MB read => HBM floor ~33 us (less if L3-resident).
//
// R5: the old kernel gathered the b-operand column-wise (stride 2496 B,
// 64 B useful per segment -> 16 VMEM requests/wave, 50% sector use, L2
// thrash on the second touch of mixed lines). New structure: each block
// streams its whole 97.5 KB row with perfectly contiguous float4 loads
// (wave = 1 KiB/load). Role of each float4 is pure arithmetic on its
// linear index: upper-triangle cells stay in registers (a-operand),
// lower-triangle cells are routed into LDS by pair index (780 pairs x
// 64 B = 49,920 B). One barrier, then a-regs multiply their LDS partner.
// LDS writes alternate bank-halves (<=2-way, free); reads are contiguous.

#define NF 40
#define NC 39
#define ED 16
#define NPAIRS 780                    // 40*39/2
#define ROW_FLOATS (NF * NC * ED)     // 24960 floats per batch row
#define ROW_F4 (ROW_FLOATS / 4)       // 6240 float4 per row
#define NTH 512
#define TRIPS ((ROW_F4 + NTH - 1) / NTH)   // 13

typedef float f32x4 __attribute__((ext_vector_type(4)));

__global__ __launch_bounds__(NTH) void ffm_interact_kernel(
        const float* __restrict__ x, float* __restrict__ out) {
    const int n = blockIdx.x;
    const int tid = threadIdx.x;
    const f32x4* __restrict__ base4 =
        (const f32x4*)(x + (size_t)n * ROW_FLOATS);

    __shared__ f32x4 bslot[NPAIRS * 4];    // 49,920 B: b-operand by pair id

    // 1) contiguous load of the whole row: g = tid + 512k walks the row
    //    linearly across the block -> every wave reads 1 KiB contiguous.
    f32x4 v[TRIPS];
    #pragma unroll
    for (int k = 0; k < TRIPS; ++k) {
        const int g = tid + k * NTH;
        if (g < ROW_F4) v[k] = base4[g];
    }

    // 2) route: decode (field f, col cc) from the linear index, pure VALU.
    //    cell c = g>>2 (16 floats per cell), quad q = g&3.
    //    upper (f <= cc): a-operand, pair p = S(f) + (cc - f), keep in reg.
    //    lower (f >  cc): b-operand of pair p = S(cc) + (f-1-cc) -> LDS.
    //    S(i) = 39i - i(i-1)/2 = i*(79-i)/2.
    int aidx[TRIPS];
    #pragma unroll
    for (int k = 0; k < TRIPS; ++k) {
        const int g = tid + k * NTH;
        aidx[k] = -1;
        if (g < ROW_F4) {
            const int c = g >> 2;
            const int q = g & 3;
            const int f = (int)((unsigned)c / NC);   // compiler magic-mul
            const int cc = c - f * NC;
            if (f <= cc) {
                const int p = ((f * (79 - f)) >> 1) + (cc - f);
                aidx[k] = p * 4 + q;
            } else {
                const int p = ((cc * (79 - cc)) >> 1) + (f - 1 - cc);
                bslot[p * 4 + q] = v[k];
            }
        }
    }
    __syncthreads();

    // 3) products: a-regs x LDS partner (reads contiguous in (p,q))
    float acc = 0.0f;
    #pragma unroll
    for (int k = 0; k < TRIPS; ++k) {
        if (aidx[k] >= 0) {
            const f32x4 b = bslot[aidx[k]];
            acc = fmaf(v[k][0], b[0], acc);
            acc = fmaf(v[k][1], b[1], acc);
            acc = fmaf(v[k][2], b[2], acc);
            acc = fmaf(v[k][3], b[3], acc);
        }
    }

    // wave-64 reduce, then cross-wave via LDS
    #pragma unroll
    for (int off = 32; off > 0; off >>= 1)
        acc += __shfl_down(acc, off, 64);

    __shared__ float wave_sum[NTH / 64];
    if ((tid & 63) == 0) wave_sum[tid >> 6] = acc;
    __syncthreads();
    if (tid == 0) {
        float s = 0.0f;
        #pragma unroll
        for (int w = 0; w < NTH / 64; ++w) s += wave_sum[w];
        out[n] = s;
    }
}

extern "C" void kernel_launch(void* const* d_in, const int* in_sizes, int n_in,
                              void* d_out, int out_size, void* d_ws, size_t ws_size,
                              hipStream_t stream) {
    const float* x = (const float*)d_in[0];
    float* out = (float*)d_out;
    const int bs = in_sizes[0] / ROW_FLOATS;   // 2048
    ffm_interact_kernel<<<bs, NTH, 0, stream>>>(x, out);
}

// Round 2
// 258.032 us; speedup vs baseline: 1.0569x; 1.0569x over previous
//
#include <hip/hip_runtime.h>

// FieldAwareFMLayer: x (bs, 40, 39, 16) fp32.
// out[n] = sum_{0<=i<=j<=38} dot(x[n,i,j,:], x[n,j+1,i,:])
//
// R6 = revert to R4 (best known, 254.9-256.9 us).
// R5 post-mortem: routing the b-operand through LDS regressed +16 us.
// Measured decomposition: dur_us ~= 2 harness poison-fills (~242 us,
// 83-85% of HBM peak, not addressable) + kernel (~15 us). R4's kernel
// moves 204.5 MB in ~15 us = 13.6 TB/s effective -- ABOVE HBM peak, so
// the input is L3/L2-resident and the scattered 64-B b-side requests
// are already absorbed by the cache hierarchy. The LDS round-trip only
// added a full-block barrier (serializing all 13 loads before any FMA),
// cut occupancy 4->3 blocks/CU (50 KB LDS), and raised VGPR pressure.
//
// R4 structure: 14 independent float4 loads per thread, pure-VALU
// triangular index decode (no memory op gates addresses), per-k
// independent load->FMA chains, wave-64 + LDS reduce.

#define NF 40
#define NC 39
#define ED 16
#define NPAIRS 780
#define ROW_FLOATS (NF * NC * ED)     // 24960 floats per batch row
#define NTASKS (NPAIRS * 4)           // one float4 partial-dot per task = 3120
#define NTH 512
#define TRIPS ((NTASKS + NTH - 1) / NTH)   // 7

typedef float f32x4 __attribute__((ext_vector_type(4)));

__global__ __launch_bounds__(NTH) void ffm_interact_kernel(
        const float* __restrict__ x, float* __restrict__ out) {
    const int n = blockIdx.x;
    const int tid = threadIdx.x;
    const int q = tid & 3;            // quad within embedding
    const int p0 = tid >> 2;          // p_k = p0 + 128*k  (512k>>2, no carry)
    const f32x4* __restrict__ base4 =
        (const f32x4*)(x + (size_t)n * ROW_FLOATS);

    // 1) arithmetic index decode (no memory dependency):
    //    pair p -> (i,j): i = floor((79 - sqrt(6241 - 8p))/2), guarded;
    //    S(i) = 39i - i(i-1)/2; j = i + p - S(i).
    int aoff[TRIPS], boff[TRIPS];
    #pragma unroll
    for (int k = 0; k < TRIPS; ++k) {
        int p = p0 + 128 * k;
        p = p < NPAIRS ? p : (NPAIRS - 1);       // clamp tail (masked below)
        const float disc = 6241.0f - 8.0f * (float)p;
        int i = (int)((79.0f - __builtin_sqrtf(disc)) * 0.5f);
        int Si = 39 * i - ((i * (i - 1)) >> 1);
        if (p < Si) { --i; Si = 39 * i - ((i * (i - 1)) >> 1); }
        else { const int Si1 = Si + (NC - i); if (p >= Si1) { ++i; Si = Si1; } }
        const int j = i + (p - Si);
        aoff[k] = (i * NC + j) * 4 + q;          // a = (i, j)
        boff[k] = ((j + 1) * NC + i) * 4 + q;    // b = (j+1, i)
    }

    // 2) all global loads batched -> 14 outstanding 16B loads per thread
    f32x4 av[TRIPS], bv[TRIPS];
    #pragma unroll
    for (int k = 0; k < TRIPS; ++k)
        av[k] = __builtin_nontemporal_load(&base4[aoff[k]]);
    #pragma unroll
    for (int k = 0; k < TRIPS; ++k)
        bv[k] = __builtin_nontemporal_load(&base4[boff[k]]);

    // 3) FMAs, tail-masked
    float acc = 0.0f;
    #pragma unroll
    for (int k = 0; k < TRIPS; ++k) {
        const float m = ((tid + k * NTH) < NTASKS) ? 1.0f : 0.0f;
        acc = fmaf(m * av[k][0], bv[k][0], acc);
        acc = fmaf(m * av[k][1], bv[k][1], acc);
        acc = fmaf(m * av[k][2], bv[k][2], acc);
        acc = fmaf(m * av[k][3], bv[k][3], acc);
    }

    // wave-64 reduce, then cross-wave via LDS
    #pragma unroll
    for (int off = 32; off > 0; off >>= 1)
        acc += __shfl_down(acc, off, 64);

    __shared__ float wave_sum[NTH / 64];
    if ((tid & 63) == 0) wave_sum[tid >> 6] = acc;
    __syncthreads();
    if (tid == 0) {
        float s = 0.0f;
        #pragma unroll
        for (int w = 0; w < NTH / 64; ++w) s += wave_sum[w];
        out[n] = s;
    }
}

extern "C" void kernel_launch(void* const* d_in, const int* in_sizes, int n_in,
                              void* d_out, int out_size, void* d_ws, size_t ws_size,
                              hipStream_t stream) {
    const float* x = (const float*)d_in[0];
    float* out = (float*)d_out;
    const int bs = in_sizes[0] / ROW_FLOATS;   // 2048
    ffm_interact_kernel<<<bs, NTH, 0, stream>>>(x, out);
}